// Round 1
// baseline (14322.717 us; speedup 1.0000x reference)
//
#include <hip/hip_runtime.h>
#include <hip/hip_bf16.h>

// RNN scan on MI355X — round 9.
// k1: unchanged retiled xproj; additionally clears the 8 exchange flags
//     (flags live in d_out, rewritten by the epilogue after last use).
// k2: COLUMN-SPLIT scan: 8 blocks = 4 batch-groups x 2 column-halves.
//     Per block: 256 cols, 8 waves x 32 cols, ALL of W_h in registers
//     (wfA[2][16] = 128 VGPR/wave). Halves exchange their h-half per step
//     via agent-scope atomics aliased into xw[t][own cols] (bytes already
//     consumed by xv earlier in the same step by the same wave), gated by
//     a release flag per (group,half). Own-half MFMAs hide the coherent
//     load latency. Spins are bounded -> no hang even if non-resident.

#define T_STEPS 1024
#define HID     512

typedef __attribute__((ext_vector_type(8))) short  short8;   // 8 bf16 (MFMA A/B frag)
typedef __attribute__((ext_vector_type(4))) short  short4_t; // 4 bf16 (8 B)
typedef __attribute__((ext_vector_type(4))) float  f32x4;    // MFMA C/D frag
typedef __attribute__((ext_vector_type(4))) float  float4_t;

typedef unsigned short     ushort_t;
typedef unsigned int       uint_t;
typedef unsigned long long ull_t;

__device__ __forceinline__ ushort_t f2bf(float f) {
    union { float f; uint_t u; } c; c.f = f;
    uint_t u = c.u;
    return (ushort_t)((u + 0x7fffu + ((u >> 16) & 1u)) >> 16);   // RNE
}
__device__ __forceinline__ float bf2f(ushort_t h) {
    union { uint_t u; float f; } c; c.u = ((uint_t)h) << 16;
    return c.f;
}
// tanh(x) = 1 - 2/(e^{2x}+1); exp2-based, saturates correctly at +/-1.
__device__ __forceinline__ float tanh_fast(float x) {
    float t = __builtin_amdgcn_exp2f(x * 2.88539008f);   // e^{2x}
    return 1.0f - 2.0f * __builtin_amdgcn_rcpf(t + 1.0f);
}

// ---------------------------------------------------------------------------
// k1: xw[t][b][n] = bf16(x[b,t,:] @ W_x + b_x + b_h). Transposed MFMA:
// A = W_x^T (m = n), B = x^T (n-operand = b).
// Grid (2, 256), 512 threads: WG tile = 4 t x 64 b x 256 n.
// ---------------------------------------------------------------------------
__global__ __launch_bounds__(512) void k1_xproj(
    const float* __restrict__ x, const float* __restrict__ Wx,
    const float* __restrict__ bx, const float* __restrict__ bh,
    ushort_t* __restrict__ xw, uint_t* __restrict__ flags)
{
    // clear exchange flags for k2 (visible at kernel end; stream-ordered)
    if (blockIdx.x == 0 && blockIdx.y == 0 && threadIdx.x < 8)
        flags[(threadIdx.x >> 1) * 16 + (threadIdx.x & 1)] = 0;

    __shared__ __align__(16) ushort_t Wl[256 * 40];      // [n_local][k]
    __shared__ __align__(16) ushort_t Xl[4][64 * 40];    // [tt][b][k]

    const int n0    = blockIdx.x * 256;
    const int t0    = blockIdx.y * 4;
    const int tid   = threadIdx.x;
    const int wave  = tid >> 6;
    const int lane  = tid & 63;
    const int lm    = lane & 15;
    const int quad  = lane >> 4;
    const int t_loc = wave & 3;
    const int nsub  = (wave >> 2) * 128;

    f32x4 acc[8][4];
    #pragma unroll
    for (int mt = 0; mt < 8; ++mt)
        #pragma unroll
        for (int bt = 0; bt < 4; ++bt) acc[mt][bt] = (f32x4){0.f, 0.f, 0.f, 0.f};

    const int wk = tid >> 4, wc = (tid & 15) * 16;   // W staging: k-row, 16 n's
    const int xb = tid >> 3, xc = (tid & 7) * 4;     // X staging: b-row, 4 k's

    for (int kb = 0; kb < 16; ++kb) {
        { // stage W_x swizzled: Wl[n][k] = Wx[kb*32+wk][n0+wc+j]
            const float* wp = Wx + (size_t)(kb * 32 + wk) * HID + n0 + wc;
            #pragma unroll
            for (int j = 0; j < 16; ++j) Wl[(wc + j) * 40 + wk] = f2bf(wp[j]);
        }
        #pragma unroll
        for (int tt = 0; tt < 4; ++tt) { // stage x rows, b64 writes
            const float* ap = x + ((size_t)xb * T_STEPS + t0 + tt) * HID + kb * 32 + xc;
            float4_t v = *(const float4_t*)ap;
            short4_t pk;
            #pragma unroll
            for (int j = 0; j < 4; ++j) pk[j] = (short)f2bf(v[j]);
            *(short4_t*)&Xl[tt][xb * 40 + xc] = pk;
        }
        __syncthreads();
        short8 afr[8];
        #pragma unroll
        for (int mt = 0; mt < 8; ++mt)
            afr[mt] = *(const short8*)&Wl[(nsub + mt * 16 + lm) * 40 + quad * 8];
        #pragma unroll
        for (int bt = 0; bt < 4; ++bt) {
            short8 bfr = *(const short8*)&Xl[t_loc][(bt * 16 + lm) * 40 + quad * 8];
            #pragma unroll
            for (int mt = 0; mt < 8; ++mt)
                acc[mt][bt] = __builtin_amdgcn_mfma_f32_16x16x32_bf16(afr[mt], bfr, acc[mt][bt], 0, 0, 0);
        }
        __syncthreads();
    }

    // D layout: col = b = lm (+bt*16), row = n_local = quad*4+r (+nsub+mt*16)
    #pragma unroll
    for (int mt = 0; mt < 8; ++mt) {
        float biasv[4];
        #pragma unroll
        for (int r = 0; r < 4; ++r) {
            int n = n0 + nsub + mt * 16 + quad * 4 + r;
            biasv[r] = bx[n] + bh[n];
        }
        #pragma unroll
        for (int bt = 0; bt < 4; ++bt) {
            short4_t pk;
            #pragma unroll
            for (int r = 0; r < 4; ++r) pk[r] = (short)f2bf(acc[mt][bt][r] + biasv[r]);
            *(short4_t*)&xw[((size_t)(t0 + t_loc) * 64 + bt * 16 + lm) * HID
                            + n0 + nsub + mt * 16 + quad * 4] = pk;
        }
    }
}

// ---------------------------------------------------------------------------
// k2: grid = 8 blocks (g = bid>>1 batch-group, half = bid&1 column half),
// 512 threads (8 waves, 2/SIMD). Wave owns 32 cols: wfA[2][16] all-register.
// LDS hT[2][4096]: own-half h frags, frag-linear, double-buffered (16 KB).
// hT element (b,k_l): ((k_l>>5)*64 + ((k_l>>3)&3)*16 + b)*8 + (k_l&7).
// Exchange: own h_{t+1} half atomic-stored into xw[t][g rows][own cols]
// (those bytes were consumed as xv by the same wave at step-t start);
// partner reads them with agent-scope atomic loads after flag >= t+1.
// ---------------------------------------------------------------------------
__global__ __launch_bounds__(512, 2) void k2_scan(
    ushort_t* __restrict__ xw, const float* __restrict__ Wh,
    const float* __restrict__ Wfc, const float* __restrict__ bfc,
    float* __restrict__ out)
{
    __shared__ __align__(16) ushort_t hT[2][4096];

    const int tid   = threadIdx.x;
    const int wave  = tid >> 6;
    const int lane  = tid & 63;
    const int lm    = lane & 15;
    const int quad  = lane >> 4;
    const int g     = blockIdx.x >> 1;       // batch group: rows g*16..g*16+15
    const int halfP = blockIdx.x & 1;        // owned column half
    const int halfQ = halfP ^ 1;
    const int colb  = halfP * 256 + wave * 32;   // wave's first output column

    uint_t* flags = (uint_t*)out;            // flag(g,h) at out[g*16+h]
    uint_t* flagP = flags + g * 16 + halfP;
    uint_t* flagQ = flags + g * 16 + halfQ;

    // ---- W_h A-fragments, FULL k range, all in registers (128 VGPR) ----
    short8 wfA[2][16];
    #pragma unroll
    for (int mt = 0; mt < 2; ++mt) {
        const int n = colb + mt * 16 + lm;
        #pragma unroll
        for (int kt = 0; kt < 16; ++kt) {
            short8 w;
            #pragma unroll
            for (int j = 0; j < 8; ++j)
                w[j] = (short)f2bf(Wh[(size_t)(kt * 32 + quad * 8 + j) * HID + n]);
            wfA[mt][kt] = w;
        }
    }

    // per-lane xw pointer: row g*16+lm of xw[t], own cols (also the outbox!)
    const ushort_t* xp = xw + ((size_t)g * 16 + lm) * HID + colb + quad * 4;
    uint_t fpre = 0;   // preloaded partner flag (avoids spin-latency at step start)

    for (int t = 0; t < T_STEPS; ++t, xp += (size_t)64 * HID) {
        short4_t xv[2];
        #pragma unroll
        for (int mt = 0; mt < 2; ++mt) xv[mt] = *(const short4_t*)(xp + mt * 16);

        // fixed-order partial accumulators: accL = k[0,256), accH = k[256,512)
        f32x4 accL[2], accH[2];
        #pragma unroll
        for (int mt = 0; mt < 2; ++mt) {
            accL[mt] = (f32x4){0.f, 0.f, 0.f, 0.f};
            accH[mt] = (f32x4){0.f, 0.f, 0.f, 0.f};
        }

        if (t > 0) {
            // partner must have published h_t (flag >= t); usually pre-satisfied
            if (fpre < (uint_t)t) {
                int guard = 0;
                while (__hip_atomic_load(flagQ, __ATOMIC_ACQUIRE, __HIP_MEMORY_SCOPE_AGENT)
                           < (uint_t)t && ++guard < (1 << 14)) {}
            }
            // issue foreign-half loads first; own-kt MFMAs hide their latency
            ushort_t* fb = xw + ((size_t)(t - 1) * 64 + g * 16 + lm) * HID
                              + halfQ * 256 + quad * 8;
            union { ull_t u[2]; short8 s; } fr[8];
            #pragma unroll
            for (int kf = 0; kf < 8; ++kf) {
                ull_t* p = (ull_t*)(fb + kf * 32);
                fr[kf].u[0] = __hip_atomic_load(p,     __ATOMIC_RELAXED, __HIP_MEMORY_SCOPE_AGENT);
                fr[kf].u[1] = __hip_atomic_load(p + 1, __ATOMIC_RELAXED, __HIP_MEMORY_SCOPE_AGENT);
            }

            f32x4* accP = halfP ? accH : accL;   // own half's accumulator
            f32x4* accQ = halfP ? accL : accH;   // foreign half's accumulator

            const ushort_t* cur = hT[t & 1];
            #pragma unroll
            for (int kt = 0; kt < 8; ++kt) {     // own half: B from LDS
                short8 b = *(const short8*)&cur[(kt * 64 + lane) * 8];
                accP[0] = __builtin_amdgcn_mfma_f32_16x16x32_bf16(wfA[0][halfP * 8 + kt], b, accP[0], 0, 0, 0);
                accP[1] = __builtin_amdgcn_mfma_f32_16x16x32_bf16(wfA[1][halfP * 8 + kt], b, accP[1], 0, 0, 0);
            }
            #pragma unroll
            for (int kf = 0; kf < 8; ++kf) {     // foreign half: B from regs
                accQ[0] = __builtin_amdgcn_mfma_f32_16x16x32_bf16(wfA[0][halfQ * 8 + kf], fr[kf].s, accQ[0], 0, 0, 0);
                accQ[1] = __builtin_amdgcn_mfma_f32_16x16x32_bf16(wfA[1][halfQ * 8 + kf], fr[kf].s, accQ[1], 0, 0, 0);
            }
        }

        // h_{t+1} = tanh(accL + accH + xw); write LDS (own frags) + publish
        ushort_t* nxt = hT[(t + 1) & 1];
        #pragma unroll
        for (int mt = 0; mt < 2; ++mt) {
            float v0 = tanh_fast(accL[mt][0] + accH[mt][0] + bf2f((ushort_t)xv[mt][0]));
            float v1 = tanh_fast(accL[mt][1] + accH[mt][1] + bf2f((ushort_t)xv[mt][1]));
            float v2 = tanh_fast(accL[mt][2] + accH[mt][2] + bf2f((ushort_t)xv[mt][2]));
            float v3 = tanh_fast(accL[mt][3] + accH[mt][3] + bf2f((ushort_t)xv[mt][3]));
            union { short4_t v; ull_t u64; __hip_bfloat162 h[2]; } cv;
            cv.h[0] = __float22bfloat162_rn(float2{v0, v1});
            cv.h[1] = __float22bfloat162_rn(float2{v2, v3});
            // own LDS frag: k_l = wave*32 + mt*16 + quad*4 + r
            *(short4_t*)&nxt[((wave * 4 + mt * 2 + (quad >> 1)) * 16 + lm) * 8
                             + (quad & 1) * 4] = cv.v;
            // publish to partner: overwrite xw[t][row g*16+lm][own col] (consumed above)
            __hip_atomic_store((ull_t*)(xp + mt * 16), cv.u64,
                               __ATOMIC_RELAXED, __HIP_MEMORY_SCOPE_AGENT);
        }

        __syncthreads();   // drains each wave's vmcnt/lgkmcnt before barrier
        if (tid == 0) {
            __threadfence();
            __hip_atomic_fetch_add(flagP, 1u, __ATOMIC_RELEASE, __HIP_MEMORY_SCOPE_AGENT);
        }
        // preload partner flag; overlaps with next step's xv/A setup
        fpre = __hip_atomic_load(flagQ, __ATOMIC_ACQUIRE, __HIP_MEMORY_SCOPE_AGENT);
    }

    // ---- fused FC epilogue: half-0 blocks only (full 512-k dot) ----
    if (halfP == 0) {
        if (fpre < (uint_t)T_STEPS) {
            int guard = 0;
            while (__hip_atomic_load(flagQ, __ATOMIC_ACQUIRE, __HIP_MEMORY_SCOPE_AGENT)
                       < (uint_t)T_STEPS && ++guard < (1 << 14)) {}
        }
        const ushort_t* fin  = hT[T_STEPS & 1];   // own half of h_T (k 0..255)
        ushort_t* fb_e = xw + ((size_t)(T_STEPS - 1) * 64 + g * 16) * HID + 256;
        #pragma unroll
        for (int bb = 0; bb < 2; ++bb) {
            const int b = wave * 2 + bb;
            float s = 0.f;
            if (lane < 32) {                       // k = lane*8 .. +8 (own, LDS)
                short8 hv = *(const short8*)&fin[(((lane >> 2) * 64 + (lane & 3) * 16 + b) * 8)];
                #pragma unroll
                for (int j = 0; j < 8; ++j)
                    s += bf2f((ushort_t)hv[j]) * Wfc[lane * 8 + j];
            } else {                               // k = 256 + (lane-32)*8 (foreign)
                ull_t* p = (ull_t*)(fb_e + (size_t)b * HID + (lane - 32) * 8);
                union { ull_t u[2]; short8 s8; } hv;
                hv.u[0] = __hip_atomic_load(p,     __ATOMIC_RELAXED, __HIP_MEMORY_SCOPE_AGENT);
                hv.u[1] = __hip_atomic_load(p + 1, __ATOMIC_RELAXED, __HIP_MEMORY_SCOPE_AGENT);
                #pragma unroll
                for (int j = 0; j < 8; ++j)
                    s += bf2f((ushort_t)hv.s8[j]) * Wfc[lane * 8 + j];
            }
            #pragma unroll
            for (int off = 32; off; off >>= 1) s += __shfl_down(s, off, 64);
            if (lane == 0) out[g * 16 + b] = s + bfc[0];
        }
    }
}

// ---------------------------------------------------------------------------
extern "C" void kernel_launch(void* const* d_in, const int* in_sizes, int n_in,
                              void* d_out, int out_size, void* d_ws, size_t ws_size,
                              hipStream_t stream)
{
    const float* x   = (const float*)d_in[0];
    const float* Wx  = (const float*)d_in[1];
    const float* bx  = (const float*)d_in[2];
    const float* Wh  = (const float*)d_in[3];
    const float* bh  = (const float*)d_in[4];
    const float* Wfc = (const float*)d_in[5];
    const float* bfc = (const float*)d_in[6];
    float* out = (float*)d_out;

    // ws: xw bf16 [1024 t][64 b][512 n] = 64 MiB (exchange aliases into it)
    ushort_t* xw = (ushort_t*)d_ws;

    k1_xproj<<<dim3(2, 256), 512, 0, stream>>>(x, Wx, bx, bh, xw, (uint_t*)out);
    k2_scan <<<dim3(8),      512, 0, stream>>>(xw, Wh, Wfc, bfc, out);
}

// Round 2
// 2742.915 us; speedup vs baseline: 5.2217x; 5.2217x over previous
//
#include <hip/hip_runtime.h>
#include <hip/hip_bf16.h>

// RNN scan on MI355X — round 10.
// Post-r9: per-step cross-CU sync via agent-scope atomics costs ~12 us/step
// (L1/L2 invalidate + writeback each step) — scan stays on 4 CUs.
// r10 vs r8: LDS-port is the binding resource (256 ds_read_b128/step = 3072cy
// > MFMA 2483cy). Shift W_h split from 12/4 to 13/3 reg/LDS (wfA[4][13] =
// 208 regs, Wl 96 KB): A-frag LDS reads 16 -> 12 per wave per step.
// xv load moved after the kt-loop to keep peak register pressure at r8 level.
// k1: W staging vectorized (4x float4 instead of 16 scalar loads).

#define T_STEPS 1024
#define HID     512

typedef __attribute__((ext_vector_type(8))) short  short8;   // 8 bf16 (MFMA A/B frag)
typedef __attribute__((ext_vector_type(4))) short  short4_t; // 4 bf16 (8 B)
typedef __attribute__((ext_vector_type(4))) float  f32x4;    // MFMA C/D frag
typedef __attribute__((ext_vector_type(4))) float  float4_t;

typedef unsigned short ushort_t;
typedef unsigned int   uint_t;

__device__ __forceinline__ ushort_t f2bf(float f) {
    union { float f; uint_t u; } c; c.f = f;
    uint_t u = c.u;
    return (ushort_t)((u + 0x7fffu + ((u >> 16) & 1u)) >> 16);   // RNE
}
__device__ __forceinline__ float bf2f(ushort_t h) {
    union { uint_t u; float f; } c; c.u = ((uint_t)h) << 16;
    return c.f;
}
// tanh(x) = 1 - 2/(e^{2x}+1); exp2-based, saturates correctly at +/-1.
__device__ __forceinline__ float tanh_fast(float x) {
    float t = __builtin_amdgcn_exp2f(x * 2.88539008f);   // e^{2x}
    return 1.0f - 2.0f * __builtin_amdgcn_rcpf(t + 1.0f);
}

// ---------------------------------------------------------------------------
// k1: xw[t][b][n] = bf16(x[b,t,:] @ W_x + b_x + b_h). Transposed MFMA:
// A = W_x^T (m = n), B = x^T (n-operand = b).
// Grid (2, 256), 512 threads: WG tile = 4 t x 64 b x 256 n.
// Wave w: t_loc = w&3, nsub = (w>>2)*128 -> 8 mt x 4 bt acc (128 regs).
// ---------------------------------------------------------------------------
__global__ __launch_bounds__(512) void k1_xproj(
    const float* __restrict__ x, const float* __restrict__ Wx,
    const float* __restrict__ bx, const float* __restrict__ bh,
    ushort_t* __restrict__ xw)
{
    __shared__ __align__(16) ushort_t Wl[256 * 40];      // [n_local][k]
    __shared__ __align__(16) ushort_t Xl[4][64 * 40];    // [tt][b][k]

    const int n0    = blockIdx.x * 256;
    const int t0    = blockIdx.y * 4;
    const int tid   = threadIdx.x;
    const int wave  = tid >> 6;
    const int lane  = tid & 63;
    const int lm    = lane & 15;
    const int quad  = lane >> 4;
    const int t_loc = wave & 3;
    const int nsub  = (wave >> 2) * 128;

    f32x4 acc[8][4];
    #pragma unroll
    for (int mt = 0; mt < 8; ++mt)
        #pragma unroll
        for (int bt = 0; bt < 4; ++bt) acc[mt][bt] = (f32x4){0.f, 0.f, 0.f, 0.f};

    const int wk = tid >> 4, wc = (tid & 15) * 16;   // W staging: k-row, 16 n's
    const int xb = tid >> 3, xc = (tid & 7) * 4;     // X staging: b-row, 4 k's

    for (int kb = 0; kb < 16; ++kb) {
        { // stage W_x swizzled: Wl[n][k] = Wx[kb*32+wk][n0+wc+..] — float4 loads
            const float4_t* wp = (const float4_t*)(Wx + (size_t)(kb * 32 + wk) * HID + n0 + wc);
            #pragma unroll
            for (int jj = 0; jj < 4; ++jj) {
                float4_t v = wp[jj];
                #pragma unroll
                for (int j = 0; j < 4; ++j)
                    Wl[(wc + jj * 4 + j) * 40 + wk] = f2bf(v[j]);
            }
        }
        #pragma unroll
        for (int tt = 0; tt < 4; ++tt) { // stage x rows, b64 writes
            const float* ap = x + ((size_t)xb * T_STEPS + t0 + tt) * HID + kb * 32 + xc;
            float4_t v = *(const float4_t*)ap;
            short4_t pk;
            #pragma unroll
            for (int j = 0; j < 4; ++j) pk[j] = (short)f2bf(v[j]);
            *(short4_t*)&Xl[tt][xb * 40 + xc] = pk;
        }
        __syncthreads();
        short8 afr[8];
        #pragma unroll
        for (int mt = 0; mt < 8; ++mt)
            afr[mt] = *(const short8*)&Wl[(nsub + mt * 16 + lm) * 40 + quad * 8];
        #pragma unroll
        for (int bt = 0; bt < 4; ++bt) {
            short8 bfr = *(const short8*)&Xl[t_loc][(bt * 16 + lm) * 40 + quad * 8];
            #pragma unroll
            for (int mt = 0; mt < 8; ++mt)
                acc[mt][bt] = __builtin_amdgcn_mfma_f32_16x16x32_bf16(afr[mt], bfr, acc[mt][bt], 0, 0, 0);
        }
        __syncthreads();
    }

    // D layout: col = b = lm (+bt*16), row = n_local = quad*4+r (+nsub+mt*16)
    #pragma unroll
    for (int mt = 0; mt < 8; ++mt) {
        float biasv[4];
        #pragma unroll
        for (int r = 0; r < 4; ++r) {
            int n = n0 + nsub + mt * 16 + quad * 4 + r;
            biasv[r] = bx[n] + bh[n];
        }
        #pragma unroll
        for (int bt = 0; bt < 4; ++bt) {
            short4_t pk;
            #pragma unroll
            for (int r = 0; r < 4; ++r) pk[r] = (short)f2bf(acc[mt][bt][r] + biasv[r]);
            *(short4_t*)&xw[((size_t)(t0 + t_loc) * 64 + bt * 16 + lm) * HID
                            + n0 + nsub + mt * 16 + quad * 4] = pk;
        }
    }
}

// ---------------------------------------------------------------------------
// k2: grid=4 x 512 threads (8 waves, 2/SIMD). Wave owns 64 cols.
// LDS (ushort):
//   hT[2][8192] : h B-frags, frag-linear, double-buffered (2 x 16 KB)
//   Wl[49152]   : W_h A-frags for k in [416,512) (96 KB)   <-- 13/3 split
// hT element (b,k): (kt*64 + ((k>>3)&3)*16 + b)*8 + (k&7), kt = k>>5.
// Wl frag c = (ktp*32 + mtg)*64 + l: m = n = mtg*16+(l&15),
//   k = (13+ktp)*32 + (l>>4)*8 + j.
// ---------------------------------------------------------------------------
__global__ __launch_bounds__(512, 2) void k2_scan(
    const ushort_t* __restrict__ xw, const float* __restrict__ Wh,
    const float* __restrict__ Wfc, const float* __restrict__ bfc,
    float* __restrict__ out)
{
    __shared__ __align__(16) ushort_t hT[2][8192];
    __shared__ __align__(16) ushort_t Wl[49152];

    const int tid  = threadIdx.x;
    const int wave = tid >> 6;
    const int lane = tid & 63;
    const int lm   = lane & 15;
    const int quad = lane >> 4;
    const int rowbase = blockIdx.x * 16;   // batch rows
    const int colb    = wave * 64;         // wave's first output column

    // h_0 = 0 (buffer 0 only; buffer 1 fully written at t=0)
    for (int i = tid; i < 8192; i += 512) hT[0][i] = 0;

    // Wl init: 3*32*64 = 6144 frags (k in [416,512))
    for (int i = 0; i < 12; ++i) {
        int c   = i * 512 + tid;
        int l   = c & 63;
        int mtg = (c >> 6) & 31;
        int ktp = c >> 11;
        int n   = mtg * 16 + (l & 15);
        int kb  = (13 + ktp) * 32 + (l >> 4) * 8;
        short8 w;
        #pragma unroll
        for (int j = 0; j < 8; ++j) w[j] = (short)f2bf(Wh[(size_t)(kb + j) * HID + n]);
        *(short8*)&Wl[(size_t)c * 8] = w;
    }

    // wfA[mt][kt]: A[m = colb+mt*16+lm][k = kt*32+quad*8+j], k in [0,416).
    // ALL register indices compile-time; 208 frag-regs.
    short8 wfA[4][13];
    #pragma unroll
    for (int mt = 0; mt < 4; ++mt) {
        const int n = colb + mt * 16 + lm;
        #pragma unroll
        for (int kt = 0; kt < 13; ++kt) {
            short8 w;
            #pragma unroll
            for (int j = 0; j < 8; ++j)
                w[j] = (short)f2bf(Wh[(size_t)(kt * 32 + quad * 8 + j) * HID + n]);
            wfA[mt][kt] = w;
        }
    }
    __syncthreads();

    // strength-reduced xw pointer (per-lane base; bump by 64*HID per step)
    const ushort_t* xp = xw + ((size_t)rowbase + lm) * HID + colb + quad * 4;

    for (int t = 0; t < T_STEPS; ++t, xp += (size_t)64 * HID) {
        f32x4 acc[4];
        #pragma unroll
        for (int mt = 0; mt < 4; ++mt) acc[mt] = (f32x4){0.f, 0.f, 0.f, 0.f};

        const ushort_t* cur = hT[t & 1];
        // k in [0,416): A from registers, B (h) from LDS
        #pragma unroll
        for (int kt = 0; kt < 13; ++kt) {
            short8 b = *(const short8*)&cur[(kt * 64 + lane) * 8];
            #pragma unroll
            for (int mt = 0; mt < 4; ++mt)
                acc[mt] = __builtin_amdgcn_mfma_f32_16x16x32_bf16(wfA[mt][kt], b, acc[mt], 0, 0, 0);
        }

        // xw loads issued here: shorter live range (kt-loop is the pressure
        // peak); still ~2 LDS+MFMA groups ahead of first use at the tail.
        short4_t xv[4];
        #pragma unroll
        for (int mt = 0; mt < 4; ++mt)
            xv[mt] = *(const short4_t*)(xp + mt * 16);

        // k in [416,512): A from LDS
        #pragma unroll
        for (int ktp = 0; ktp < 3; ++ktp) {
            short8 b = *(const short8*)&cur[((13 + ktp) * 64 + lane) * 8];
            #pragma unroll
            for (int mt = 0; mt < 4; ++mt) {
                short8 a = *(const short8*)&Wl[(size_t)((ktp * 32 + wave * 4 + mt) * 64 + lane) * 8];
                acc[mt] = __builtin_amdgcn_mfma_f32_16x16x32_bf16(a, b, acc[mt], 0, 0, 0);
            }
        }

        // h_{t+1} = tanh(acc + xw) -> other hT buffer (packed b64 stores)
        ushort_t* nxt = hT[(t + 1) & 1];
        #pragma unroll
        for (int mt = 0; mt < 4; ++mt) {
            float v0 = tanh_fast(acc[mt][0] + bf2f((ushort_t)xv[mt][0]));
            float v1 = tanh_fast(acc[mt][1] + bf2f((ushort_t)xv[mt][1]));
            float v2 = tanh_fast(acc[mt][2] + bf2f((ushort_t)xv[mt][2]));
            float v3 = tanh_fast(acc[mt][3] + bf2f((ushort_t)xv[mt][3]));
            union { short4_t v; __hip_bfloat162 h[2]; } cv;
            cv.h[0] = __float22bfloat162_rn(float2{v0, v1});
            cv.h[1] = __float22bfloat162_rn(float2{v2, v3});
            const int n = colb + mt * 16 + quad * 4;
            *(short4_t*)&nxt[((n >> 5) * 64 + ((n >> 3) & 3) * 16 + lm) * 8 + (n & 7)] = cv.v;
        }

        __syncthreads();   // ONE barrier: h_{t+1} complete before next step reads
    }

    // fused FC epilogue: out[rowbase+b] = h_T[b,:] . W_fc + b_fc
    const ushort_t* fin = hT[T_STEPS & 1];
    #pragma unroll
    for (int bb = 0; bb < 2; ++bb) {
        const int b = wave * 2 + bb;
        short8 hv = *(const short8*)&fin[(((lane >> 2) * 64 + (lane & 3) * 16 + b) * 8)];
        float s = 0.f;
        #pragma unroll
        for (int j = 0; j < 8; ++j) s += bf2f((ushort_t)hv[j]) * Wfc[lane * 8 + j];
        #pragma unroll
        for (int off = 32; off; off >>= 1) s += __shfl_down(s, off, 64);
        if (lane == 0) out[rowbase + b] = s + bfc[0];
    }
}

// ---------------------------------------------------------------------------
extern "C" void kernel_launch(void* const* d_in, const int* in_sizes, int n_in,
                              void* d_out, int out_size, void* d_ws, size_t ws_size,
                              hipStream_t stream)
{
    const float* x   = (const float*)d_in[0];
    const float* Wx  = (const float*)d_in[1];
    const float* bx  = (const float*)d_in[2];
    const float* Wh  = (const float*)d_in[3];
    const float* bh  = (const float*)d_in[4];
    const float* Wfc = (const float*)d_in[5];
    const float* bfc = (const float*)d_in[6];
    float* out = (float*)d_out;

    // ws: xw bf16 [1024 t][64 b][512 n] = 64 MiB
    ushort_t* xw = (ushort_t*)d_ws;

    k1_xproj<<<dim3(2, 256), 512, 0, stream>>>(x, Wx, bx, bh, xw);
    k2_scan <<<dim3(4),      512, 0, stream>>>(xw, Wh, Wfc, bfc, out);
}